// Round 1
// baseline (1155.011 us; speedup 1.0000x reference)
//
#include <hip/hip_runtime.h>
#include <hip/hip_bf16.h>

// WindowAttention: B=2048 windows, N=98 tokens, C=192, H=6 heads, hd=32, nw=64 masks.
// Pipeline: K0 prep (o_w->f16, bias gather) ; K1 QKV GEMM (f16 MFMA, scatter to [b][s][h][i][d]) ;
// K2 per-(b,h) attention (QK^T MFMA from global, register softmax, PV MFMA via LDS) ;
// K3 out-proj GEMM. Requires ws_size >= ~309 MB.

#define NB   2048
#define NN   98
#define CC   192
#define NH   6
#define HD   32
#define NWIN 64
#define MM   (NB * NN)          // 200704 rows
#define HEADBLK (NN * HD)       // 3136 elements per (b,s,h) slice

typedef _Float16 half8  __attribute__((ext_vector_type(8)));
typedef _Float16 half4v __attribute__((ext_vector_type(4)));
typedef float    f32x4  __attribute__((ext_vector_type(4)));

__device__ __forceinline__ f32x4 mfma16(half8 a, half8 b, f32x4 c) {
    return __builtin_amdgcn_mfma_f32_16x16x32_f16(a, b, c, 0, 0, 0);
}

// ---------------- workspace layout (bytes) ----------------
// qkv f16   : [2048][3][6][98][32]            231,211,008 B @ 0
// attn_out  : [200704][192] f16                77,070,336 B @ 231211008
// o_w f16   : [192][192]                           73,728 B @ 308281344
// bias_pre  : [6][98][98] f32                     230,496 B @ 308355072
#define WS_QKV   0ull
#define WS_AO    231211008ull
#define WS_W2    308281344ull
#define WS_BIAS  308355072ull

// ---------------- K0: small prep ----------------
__global__ __launch_bounds__(256) void wa_k0_prep(
    const float* __restrict__ o_w, const float* __restrict__ bias_table,
    const int* __restrict__ rel_index, _Float16* __restrict__ w2,
    float* __restrict__ bias_pre)
{
    int t = blockIdx.x * 256 + threadIdx.x;
    if (t < CC * CC) {
        w2[t] = (_Float16)o_w[t];
    } else if (t < CC * CC + NH * NN * NN) {
        int e = t - CC * CC;            // e = h*9604 + r
        int h = e / (NN * NN);
        int r = e - h * (NN * NN);
        bias_pre[e] = bias_table[rel_index[r] * NH + h];
    }
}

// ---------------- K1: QKV projection GEMM ----------------
// out[b][s][h][i][d] = sum_c x[b*98+i][c] * qkv_w[s*192+h*32+d][c] + qkv_b[j]
// grid: (9 n-blocks of 64, 3136 m-blocks of 64), 256 threads (4 waves).
__global__ __launch_bounds__(256) void wa_k1_qkv(
    const float* __restrict__ x, const float* __restrict__ qkv_w,
    const float* __restrict__ qkv_b, _Float16* __restrict__ qkv)
{
    const int nb = blockIdx.x;          // 0..8
    const int mb = blockIdx.y;          // 0..3135
    __shared__ __align__(16) _Float16 As[64 * 216];   // pad 192->216 (2-way bank = free)
    __shared__ __align__(16) _Float16 Bs[64 * 216];
    const int tid = threadIdx.x;

    // stage 64x192 fp32 -> f16 LDS for both A (x rows) and B (qkv_w rows)
    for (int q = tid; q < 3072; q += 256) {
        int row = q / 48;
        int c4  = (q - row * 48) * 4;
        float4 av = *(const float4*)(x + (size_t)(mb * 64 + row) * CC + c4);
        half4v ah = { (_Float16)av.x, (_Float16)av.y, (_Float16)av.z, (_Float16)av.w };
        *(half4v*)(As + row * 216 + c4) = ah;
        float4 bv = *(const float4*)(qkv_w + (size_t)(nb * 64 + row) * CC + c4);
        half4v bh = { (_Float16)bv.x, (_Float16)bv.y, (_Float16)bv.z, (_Float16)bv.w };
        *(half4v*)(Bs + row * 216 + c4) = bh;
    }
    __syncthreads();

    const int lane = tid & 63, wave = tid >> 6;
    const int l16 = lane & 15, quad = lane >> 4;

    f32x4 acc[4] = {};
    const _Float16* ap = As + (wave * 16 + l16) * 216 + quad * 8;
    #pragma unroll
    for (int kk = 0; kk < 6; ++kk) {
        half8 a = *(const half8*)(ap + kk * 32);
        #pragma unroll
        for (int nt = 0; nt < 4; ++nt) {
            half8 b = *(const half8*)(Bs + (nt * 16 + l16) * 216 + kk * 32 + quad * 8);
            acc[nt] = mfma16(a, b, acc[nt]);
        }
    }

    // epilogue: + qkv_b, scatter f16 to [b][s][h][i][d]
    #pragma unroll
    for (int nt = 0; nt < 4; ++nt) {
        int j = nb * 64 + nt * 16 + l16;        // 0..575
        float bias = qkv_b[j];
        int s  = j / CC;
        int rm = j - s * CC;
        int h  = rm >> 5;
        int d  = rm & 31;
        #pragma unroll
        for (int r = 0; r < 4; ++r) {
            int m  = mb * 64 + wave * 16 + quad * 4 + r;   // global row
            int b_ = m / NN;
            int i  = m - b_ * NN;
            qkv[((size_t)(b_ * 3 + s) * NH + h) * HEADBLK + i * HD + d] =
                (_Float16)(acc[nt][r] + bias);
        }
    }
}

// ---------------- K2: attention per (b,h) ----------------
__global__ __launch_bounds__(256) void wa_k2_attn(
    const _Float16* __restrict__ qkv, const float* __restrict__ mask,
    const float* __restrict__ bias_pre, _Float16* __restrict__ ao)
{
    const int h = blockIdx.x;           // 0..5
    const int b = blockIdx.y;           // 0..2047
    const int widx = b & (NWIN - 1);
    const _Float16* qp = qkv + ((size_t)(b * 3 + 0) * NH + h) * HEADBLK;
    const _Float16* kp = qkv + ((size_t)(b * 3 + 1) * NH + h) * HEADBLK;
    const _Float16* vp = qkv + ((size_t)(b * 3 + 2) * NH + h) * HEADBLK;

    __shared__ __align__(16) _Float16 P[112 * 136];   // probs, rows 0..111, K-pad to 128
    __shared__ __align__(16) _Float16 Vt[32 * 136];   // V transposed [d][j], j-pad to 128

    const int tid = threadIdx.x;
    // zero all of P (cols >= 112 are read by PV fragments; rest overwritten post-barrier)
    for (int idx = tid; idx < (112 * 136) / 2; idx += 256) ((unsigned int*)P)[idx] = 0u;
    // stage V transposed (coalesced global read), then zero tail j in [98,136)
    for (int idx = tid; idx < NN * HD; idx += 256) {
        int j = idx >> 5, d = idx & 31;
        Vt[d * 136 + j] = vp[idx];
    }
    for (int idx = tid; idx < 32 * 38; idx += 256) {
        int d = idx / 38;
        int j = NN + (idx - d * 38);
        Vt[d * 136 + j] = (_Float16)0.f;
    }
    __syncthreads();

    const int lane = tid & 63, wave = tid >> 6;
    const int l16 = lane & 15, quad = lane >> 4;
    const float scale = 0.17677669529663687f;   // 32^-0.5

    // ---- S = QK^T (fragments direct from global), register softmax, write P ----
    for (int mt = wave; mt < 7; mt += 4) {
        int ia = mt * 16 + l16;                 // A-fragment row (query index)
        int ic = ia < NN ? ia : NN - 1;         // clamp pad rows
        half8 aq = *(const half8*)(qp + ic * HD + quad * 8);

        f32x4 s[7];
        #pragma unroll
        for (int jt = 0; jt < 7; ++jt) {
            int jb = jt * 16 + l16;             // B-fragment row (key index)
            int jc = jb < NN ? jb : NN - 1;
            half8 bk = *(const half8*)(kp + jc * HD + quad * 8);
            f32x4 z = {};
            s[jt] = mfma16(aq, bk, z);
        }

        // scale + bias + mask (C layout: row = quad*4+r, col = l16)
        const int irow_base = mt * 16 + quad * 4;
        #pragma unroll
        for (int r = 0; r < 4; ++r) {
            int ir  = irow_base + r;
            int irc = ir < NN ? ir : NN - 1;    // pad rows get valid-but-discarded values
            const float* bp = bias_pre + (h * NN + irc) * NN;
            const float* mp = mask + ((size_t)widx * NN + irc) * NN;
            #pragma unroll
            for (int jt = 0; jt < 7; ++jt) {
                int jcol = jt * 16 + l16;
                s[jt][r] = (jcol < NN)
                    ? fmaf(s[jt][r], scale, bp[jcol] + mp[jcol])
                    : -__builtin_inff();
            }
        }

        // softmax per row: row's 112 cols live in 16 lanes x 7 regs (same quad group)
        #pragma unroll
        for (int r = 0; r < 4; ++r) {
            float mx = -__builtin_inff();
            #pragma unroll
            for (int jt = 0; jt < 7; ++jt) mx = fmaxf(mx, s[jt][r]);
            mx = fmaxf(mx, __shfl_xor(mx, 1));
            mx = fmaxf(mx, __shfl_xor(mx, 2));
            mx = fmaxf(mx, __shfl_xor(mx, 4));
            mx = fmaxf(mx, __shfl_xor(mx, 8));
            float sum = 0.f;
            #pragma unroll
            for (int jt = 0; jt < 7; ++jt) {
                float p = __expf(s[jt][r] - mx);   // exp(-inf)=0 masks pad cols
                s[jt][r] = p;
                sum += p;
            }
            sum += __shfl_xor(sum, 1);
            sum += __shfl_xor(sum, 2);
            sum += __shfl_xor(sum, 4);
            sum += __shfl_xor(sum, 8);
            float inv = 1.0f / sum;
            int prow = irow_base + r;
            #pragma unroll
            for (int jt = 0; jt < 7; ++jt)
                P[prow * 136 + jt * 16 + l16] = (_Float16)(s[jt][r] * inv);
        }
    }
    __syncthreads();

    // ---- O = P @ V : 7 m-tiles x 2 d-tiles, K = 128 (zero-padded) ----
    for (int t = wave; t < 14; t += 4) {
        int mt = t >> 1, nt = t & 1;
        f32x4 acc = {};
        #pragma unroll
        for (int kc = 0; kc < 4; ++kc) {
            half8 a = *(const half8*)(P  + (mt * 16 + l16) * 136 + kc * 32 + quad * 8);
            half8 b = *(const half8*)(Vt + (nt * 16 + l16) * 136 + kc * 32 + quad * 8);
            acc = mfma16(a, b, acc);
        }
        #pragma unroll
        for (int r = 0; r < 4; ++r) {
            int i = mt * 16 + quad * 4 + r;
            if (i < NN) {
                int d = nt * 16 + l16;
                ao[((size_t)b * NN + i) * CC + h * HD + d] = (_Float16)acc[r];
            }
        }
    }
}

// ---------------- K3: output projection GEMM ----------------
// out[m][e] = sum_c ao[m][c] * o_w[e][c] + o_b[e];  one 16x16 tile per wave.
__global__ __launch_bounds__(256) void wa_k3_proj(
    const _Float16* __restrict__ ao, const _Float16* __restrict__ w2,
    const float* __restrict__ o_b, float* __restrict__ out)
{
    const int lane = threadIdx.x & 63, wave = threadIdx.x >> 6;
    const int id = blockIdx.x * 4 + wave;       // 0..150527
    const int mt = id / 12, nt = id - mt * 12;
    const int l16 = lane & 15, quad = lane >> 4;

    const _Float16* ap = ao + (size_t)(mt * 16 + l16) * CC + quad * 8;
    const _Float16* bp = w2 + (size_t)(nt * 16 + l16) * CC + quad * 8;
    f32x4 acc = {};
    #pragma unroll
    for (int kk = 0; kk < 6; ++kk) {
        half8 a = *(const half8*)(ap + kk * 32);
        half8 b = *(const half8*)(bp + kk * 32);
        acc = mfma16(a, b, acc);
    }
    int e = nt * 16 + l16;
    float ob = o_b[e];
    #pragma unroll
    for (int r = 0; r < 4; ++r) {
        int m = mt * 16 + quad * 4 + r;
        out[(size_t)m * CC + e] = acc[r] + ob;
    }
}

// ---------------- launcher ----------------
extern "C" void kernel_launch(void* const* d_in, const int* in_sizes, int n_in,
                              void* d_out, int out_size, void* d_ws, size_t ws_size,
                              hipStream_t stream)
{
    const float* x          = (const float*)d_in[0];
    const float* mask       = (const float*)d_in[1];
    const float* qkv_w      = (const float*)d_in[2];
    const float* qkv_b      = (const float*)d_in[3];
    const float* o_w        = (const float*)d_in[4];
    const float* o_b        = (const float*)d_in[5];
    const float* bias_table = (const float*)d_in[6];
    const int*   rel_index  = (const int*)d_in[7];

    char* ws = (char*)d_ws;
    _Float16* qkv      = (_Float16*)(ws + WS_QKV);
    _Float16* ao       = (_Float16*)(ws + WS_AO);
    _Float16* w2       = (_Float16*)(ws + WS_W2);
    float*    bias_pre = (float*)(ws + WS_BIAS);
    float*    out      = (float*)d_out;

    // K0: prep (o_w cast + bias gather): 36864 + 57624 = 94488 elements
    wa_k0_prep<<<(CC * CC + NH * NN * NN + 255) / 256, 256, 0, stream>>>(
        o_w, bias_table, rel_index, w2, bias_pre);
    // K1: QKV GEMM
    wa_k1_qkv<<<dim3(9, MM / 64), 256, 0, stream>>>(x, qkv_w, qkv_b, qkv);
    // K2: attention
    wa_k2_attn<<<dim3(NH, NB), 256, 0, stream>>>(qkv, mask, bias_pre, ao);
    // K3: out projection
    wa_k3_proj<<<(MM / 16) * (CC / 16) / 4, 256, 0, stream>>>(ao, w2, o_b, out);
}

// Round 2
// 859.311 us; speedup vs baseline: 1.3441x; 1.3441x over previous
//
#include <hip/hip_runtime.h>
#include <hip/hip_bf16.h>

// WindowAttention: B=2048 windows, N=98 tokens, C=192, H=6 heads, hd=32, nw=64 masks.
// K0 prep (o_w/qkv_w->f16, bias gather); K1 QKV GEMM (A in LDS f16, B direct-global f16,
// 128x64 tile, XCD swizzle); K2 per-(b,h) attention (448 thr, K in LDS, register softmax);
// K3 out-proj (32x32 tile/wave, XCD swizzle). ws usage identical to round-1 (308.6 MB);
// f16 qkv_w copy aliased into the ao region (written by K0, consumed by K1 before K2 writes ao).

#define NB   2048
#define NN   98
#define CC   192
#define NH   6
#define HD   32
#define NWIN 64
#define MM   (NB * NN)          // 200704 rows
#define HEADBLK (NN * HD)       // 3136 elements per (b,s,h) slice

typedef _Float16 half8  __attribute__((ext_vector_type(8)));
typedef float    f32x4  __attribute__((ext_vector_type(4)));

__device__ __forceinline__ f32x4 mfma16(half8 a, half8 b, f32x4 c) {
    return __builtin_amdgcn_mfma_f32_16x16x32_f16(a, b, c, 0, 0, 0);
}

// ---------------- workspace layout (bytes) ----------------
// qkv f16   : [2048][3][6][98][32]            231,211,008 B @ 0
// attn_out  : [200704][192] f16                77,070,336 B @ 231,211,008
//   (first 221,184 B of this region alias the f16 qkv_w copy: K0 writes, K1 reads, K2 overwrites)
// o_w f16   : [192][192]                           73,728 B @ 308,281,344
// bias_pre  : [6][98][98] f32                     230,496 B @ 308,355,072   (total 308,585,568)
#define WS_QKV   0ull
#define WS_AO    231211008ull
#define WS_W2    308281344ull
#define WS_BIAS  308355072ull

// ---------------- K0: prep (o_w->f16, qkv_w->f16, bias gather) ----------------
__global__ __launch_bounds__(256) void wa_k0_prep(
    const float* __restrict__ o_w, const float* __restrict__ qkv_w,
    const float* __restrict__ bias_table, const int* __restrict__ rel_index,
    _Float16* __restrict__ w2, _Float16* __restrict__ wqh,
    float* __restrict__ bias_pre)
{
    int t = blockIdx.x * 256 + threadIdx.x;
    if (t < CC * CC) {
        w2[t] = (_Float16)o_w[t];
    } else if (t < CC * CC + 3 * CC * CC) {
        int e = t - CC * CC;
        wqh[e] = (_Float16)qkv_w[e];
    } else if (t < CC * CC + 3 * CC * CC + NH * NN * NN) {
        int e = t - 4 * CC * CC;        // e = h*9604 + r
        int h = e / (NN * NN);
        int r = e - h * (NN * NN);
        bias_pre[e] = bias_table[rel_index[r] * NH + h];
    }
}

// ---------------- K1: QKV projection GEMM ----------------
// 128x64 output tile per block; A (x rows, fp32->f16) staged in LDS; B fragments direct
// from f16 qkv_w copy. grid = 14112 linear, XCD-swizzled so one mb's 9 n-blocks share an XCD.
__global__ __launch_bounds__(256) void wa_k1_qkv(
    const float* __restrict__ x, const _Float16* __restrict__ wqh,
    const float* __restrict__ qkv_b, _Float16* __restrict__ qkv)
{
    const int id = blockIdx.x;                 // 0..14111 = 8*9*196
    const int c8 = id & 7;
    const int nb = (id >> 3) % 9;              // 0..8
    const int mb = (id / 72) * 8 + c8;         // 0..1567
    __shared__ __align__(16) _Float16 As[128 * 200];   // stride 200 f16 = 400 B (16B-aligned, 2-way banks)

    const int tid = threadIdx.x;
    // stage 128x192 fp32 -> f16 (3072 granules of 8 f16)
    for (int idx = tid; idx < 3072; idx += 256) {
        int row = idx / 24;
        int g   = idx - row * 24;
        const float* src = x + (size_t)(mb * 128 + row) * CC + g * 8;
        float4 v0 = *(const float4*)src;
        float4 v1 = *(const float4*)(src + 4);
        half8 hv = { (_Float16)v0.x, (_Float16)v0.y, (_Float16)v0.z, (_Float16)v0.w,
                     (_Float16)v1.x, (_Float16)v1.y, (_Float16)v1.z, (_Float16)v1.w };
        *(half8*)(As + row * 200 + g * 8) = hv;
    }
    __syncthreads();

    const int lane = tid & 63, wave = tid >> 6;
    const int l16 = lane & 15, quad = lane >> 4;

    const _Float16* ap = As + (wave * 32 + l16) * 200 + quad * 8;
    const _Float16* bbase = wqh + (size_t)(nb * 64 + l16) * CC + quad * 8;

    f32x4 acc[2][4] = {};
    #pragma unroll
    for (int kk = 0; kk < 6; ++kk) {
        half8 a0 = *(const half8*)(ap + kk * 32);
        half8 a1 = *(const half8*)(ap + 16 * 200 + kk * 32);
        #pragma unroll
        for (int nt = 0; nt < 4; ++nt) {
            half8 b = *(const half8*)(bbase + nt * 16 * CC + kk * 32);
            acc[0][nt] = mfma16(a0, b, acc[0][nt]);
            acc[1][nt] = mfma16(a1, b, acc[1][nt]);
        }
    }

    // epilogue: + qkv_b, scatter f16 to [b][s][h][i][d]
    int bArr[8], iArr[8];
    #pragma unroll
    for (int mi = 0; mi < 2; ++mi)
        #pragma unroll
        for (int r = 0; r < 4; ++r) {
            int m = mb * 128 + wave * 32 + mi * 16 + quad * 4 + r;
            int b_ = m / NN;
            bArr[mi * 4 + r] = b_;
            iArr[mi * 4 + r] = m - b_ * NN;
        }
    #pragma unroll
    for (int nt = 0; nt < 4; ++nt) {
        int j = nb * 64 + nt * 16 + l16;        // 0..575
        float bias = qkv_b[j];
        int s  = j / CC;
        int rm = j - s * CC;
        int h  = rm >> 5;
        int d  = rm & 31;
        #pragma unroll
        for (int mi = 0; mi < 2; ++mi)
            #pragma unroll
            for (int r = 0; r < 4; ++r) {
                int e = mi * 4 + r;
                qkv[((size_t)(bArr[e] * 3 + s) * NH + h) * HEADBLK + iArr[e] * HD + d] =
                    (_Float16)(acc[mi][nt][r] + bias);
            }
    }
}

// ---------------- K2: attention per (b,h), 448 threads = 7 waves ----------------
__global__ __launch_bounds__(448) void wa_k2_attn(
    const _Float16* __restrict__ qkv, const float* __restrict__ mask,
    const float* __restrict__ bias_pre, _Float16* __restrict__ ao)
{
    const int h = blockIdx.x;           // 0..5
    const int b = blockIdx.y;           // 0..2047
    const int widx = b & (NWIN - 1);
    const _Float16* qp = qkv + ((size_t)(b * 3 + 0) * NH + h) * HEADBLK;
    const _Float16* kp = qkv + ((size_t)(b * 3 + 1) * NH + h) * HEADBLK;
    const _Float16* vp = qkv + ((size_t)(b * 3 + 2) * NH + h) * HEADBLK;

    __shared__ __align__(16) _Float16 Kl[112 * 40];   // K rows, stride 40 (conflict-free frag reads)
    __shared__ __align__(16) _Float16 Vt[32 * 136];   // V transposed [d][j], j-pad to 128
    __shared__ __align__(16) _Float16 P[112 * 136];   // probs, K-pad to 128

    const int tid = threadIdx.x;
    // stage K: 392 granules of 8 f16, one shot
    if (tid < 392) {
        int row = tid >> 2, g = tid & 3;
        *(half8*)(Kl + row * 40 + g * 8) = *(const half8*)(kp + row * 32 + g * 8);
    }
    // zero K pad rows 98..111 (560 f16 = 280 dwords, contiguous)
    if (tid < 280) ((unsigned int*)Kl)[1960 + tid] = 0u;
    // stage V transposed (3136 = 448*7)
    for (int idx = tid; idx < NN * HD; idx += 448) {
        int j = idx >> 5, d = idx & 31;
        Vt[d * 136 + j] = vp[idx];
    }
    // zero Vt cols 98..135
    for (int idx = tid; idx < 32 * 38; idx += 448) {
        int d = idx / 38;
        Vt[d * 136 + NN + (idx - d * 38)] = (_Float16)0.f;
    }
    // zero P cols 112..127 (read by PV, never written by softmax)
    for (int idx = tid; idx < 896; idx += 448) {
        int row = idx >> 3;
        ((unsigned int*)P)[row * 68 + 56 + (idx & 7)] = 0u;
    }
    __syncthreads();

    const int lane = tid & 63, wave = tid >> 6;
    const int l16 = lane & 15, quad = lane >> 4;
    const float scale = 0.17677669529663687f;   // 32^-0.5

    // ---- S = QK^T (one m-tile per wave), register softmax, write P ----
    {
        const int mt = wave;                    // 0..6
        int ia = mt * 16 + l16;
        int ic = ia < NN ? ia : NN - 1;         // clamp pad rows
        half8 aq = *(const half8*)(qp + ic * HD + quad * 8);

        f32x4 s[7];
        #pragma unroll
        for (int jt = 0; jt < 7; ++jt) {
            half8 bk = *(const half8*)(Kl + (jt * 16 + l16) * 40 + quad * 8);
            f32x4 z = {};
            s[jt] = mfma16(aq, bk, z);
        }

        const int irow_base = mt * 16 + quad * 4;
        #pragma unroll
        for (int r = 0; r < 4; ++r) {
            int ir  = irow_base + r;
            int irc = ir < NN ? ir : NN - 1;
            const float* bp = bias_pre + (h * NN + irc) * NN;
            const float* mp = mask + ((size_t)widx * NN + irc) * NN;
            #pragma unroll
            for (int jt = 0; jt < 7; ++jt) {
                int jcol = jt * 16 + l16;
                s[jt][r] = (jcol < NN)
                    ? fmaf(s[jt][r], scale, bp[jcol] + mp[jcol])
                    : -__builtin_inff();
            }
        }

        #pragma unroll
        for (int r = 0; r < 4; ++r) {
            float mx = -__builtin_inff();
            #pragma unroll
            for (int jt = 0; jt < 7; ++jt) mx = fmaxf(mx, s[jt][r]);
            mx = fmaxf(mx, __shfl_xor(mx, 1));
            mx = fmaxf(mx, __shfl_xor(mx, 2));
            mx = fmaxf(mx, __shfl_xor(mx, 4));
            mx = fmaxf(mx, __shfl_xor(mx, 8));
            float sum = 0.f;
            #pragma unroll
            for (int jt = 0; jt < 7; ++jt) {
                float p = __expf(s[jt][r] - mx);
                s[jt][r] = p;
                sum += p;
            }
            sum += __shfl_xor(sum, 1);
            sum += __shfl_xor(sum, 2);
            sum += __shfl_xor(sum, 4);
            sum += __shfl_xor(sum, 8);
            float inv = 1.0f / sum;
            int prow = irow_base + r;
            #pragma unroll
            for (int jt = 0; jt < 7; ++jt)
                P[prow * 136 + jt * 16 + l16] = (_Float16)(s[jt][r] * inv);
        }
    }
    __syncthreads();

    // ---- O = P @ V : 14 tiles over 7 waves, K = 128 (zero-padded) ----
    #pragma unroll
    for (int ti = 0; ti < 2; ++ti) {
        int t = wave * 2 + ti;
        int mt = t >> 1, nt = t & 1;
        f32x4 acc = {};
        #pragma unroll
        for (int kc = 0; kc < 4; ++kc) {
            half8 a = *(const half8*)(P  + (mt * 16 + l16) * 136 + kc * 32 + quad * 8);
            half8 b = *(const half8*)(Vt + (nt * 16 + l16) * 136 + kc * 32 + quad * 8);
            acc = mfma16(a, b, acc);
        }
        #pragma unroll
        for (int r = 0; r < 4; ++r) {
            int i = mt * 16 + quad * 4 + r;
            if (i < NN) {
                int d = nt * 16 + l16;
                ao[((size_t)b * NN + i) * CC + h * HD + d] = (_Float16)acc[r];
            }
        }
    }
}

// ---------------- K3: output projection, 32x32 tile per wave ----------------
__global__ __launch_bounds__(256) void wa_k3_proj(
    const _Float16* __restrict__ ao, const _Float16* __restrict__ w2,
    const float* __restrict__ o_b, float* __restrict__ out)
{
    const int id = blockIdx.x;                 // 0..9407 = 8*6*196
    const int c8 = id & 7;
    const int nt = (id >> 3) % 6;
    const int msuper = (id / 48) * 8 + c8;     // 0..1567
    const int lane = threadIdx.x & 63, wave = threadIdx.x >> 6;
    const int l16 = lane & 15, quad = lane >> 4;

    const int m0 = msuper * 128 + wave * 32;
    const int e0 = nt * 32;
    const _Float16* ap = ao + (size_t)(m0 + l16) * CC + quad * 8;
    const _Float16* bp = w2 + (size_t)(e0 + l16) * CC + quad * 8;

    f32x4 acc[2][2] = {};
    #pragma unroll
    for (int kk = 0; kk < 6; ++kk) {
        half8 a0 = *(const half8*)(ap + kk * 32);
        half8 a1 = *(const half8*)(ap + 16 * CC + kk * 32);
        half8 b0 = *(const half8*)(bp + kk * 32);
        half8 b1 = *(const half8*)(bp + 16 * CC + kk * 32);
        acc[0][0] = mfma16(a0, b0, acc[0][0]);
        acc[0][1] = mfma16(a0, b1, acc[0][1]);
        acc[1][0] = mfma16(a1, b0, acc[1][0]);
        acc[1][1] = mfma16(a1, b1, acc[1][1]);
    }
    #pragma unroll
    for (int ni = 0; ni < 2; ++ni) {
        int e = e0 + ni * 16 + l16;
        float ob = o_b[e];
        #pragma unroll
        for (int mi = 0; mi < 2; ++mi)
            #pragma unroll
            for (int r = 0; r < 4; ++r) {
                int m = m0 + mi * 16 + quad * 4 + r;
                out[(size_t)m * CC + e] = acc[mi][ni][r] + ob;
            }
    }
}

// ---------------- launcher ----------------
extern "C" void kernel_launch(void* const* d_in, const int* in_sizes, int n_in,
                              void* d_out, int out_size, void* d_ws, size_t ws_size,
                              hipStream_t stream)
{
    const float* x          = (const float*)d_in[0];
    const float* mask       = (const float*)d_in[1];
    const float* qkv_w      = (const float*)d_in[2];
    const float* qkv_b      = (const float*)d_in[3];
    const float* o_w        = (const float*)d_in[4];
    const float* o_b        = (const float*)d_in[5];
    const float* bias_table = (const float*)d_in[6];
    const int*   rel_index  = (const int*)d_in[7];

    char* ws = (char*)d_ws;
    _Float16* qkv      = (_Float16*)(ws + WS_QKV);
    _Float16* ao       = (_Float16*)(ws + WS_AO);
    _Float16* wqh      = (_Float16*)(ws + WS_AO);   // alias: consumed by K1 before K2 writes ao
    _Float16* w2       = (_Float16*)(ws + WS_W2);
    float*    bias_pre = (float*)(ws + WS_BIAS);
    float*    out      = (float*)d_out;

    // K0: prep: 36864 (o_w) + 110592 (qkv_w) + 57624 (bias) elements
    wa_k0_prep<<<(4 * CC * CC + NH * NN * NN + 255) / 256, 256, 0, stream>>>(
        o_w, qkv_w, bias_table, rel_index, w2, wqh, bias_pre);
    // K1: QKV GEMM, 128x64 tiles, XCD-swizzled linear grid
    wa_k1_qkv<<<14112, 256, 0, stream>>>(x, wqh, qkv_b, qkv);
    // K2: attention
    wa_k2_attn<<<dim3(NH, NB), 448, 0, stream>>>(qkv, mask, bias_pre, ao);
    // K3: out projection, XCD-swizzled linear grid
    wa_k3_proj<<<9408, 256, 0, stream>>>(ao, w2, o_b, out);
}